// Round 12
// baseline (308.429 us; speedup 1.0000x reference)
//
#include <hip/hip_runtime.h>

#define Ssz 2048
#define Dd  128
#define Hh  8
#define Bb  2
#define HDp 1024
#define NBLK 512

typedef unsigned short u16;
typedef unsigned int   u32;

typedef __attribute__((ext_vector_type(8))) short bf16x8;   // 8 bf16 = 4 VGPRs
typedef __attribute__((ext_vector_type(4))) float f32x4;    // C/D frag

union frag_cast { uint4 u; bf16x8 v; };

__device__ __forceinline__ float bflo(u32 w) { return __uint_as_float(w << 16); }
__device__ __forceinline__ u16 f2bf(float f) {
    u32 x = __float_as_uint(f);
    u32 r = x + 0x7fffu + ((x >> 16) & 1u);
    return (u16)(r >> 16);
}
__device__ __forceinline__ u32 pack2(float a, float b) {
    return (u32)f2bf(a) | ((u32)f2bf(b) << 16);
}
__device__ __forceinline__ bf16x8 ldfrag_f32(const float* p) {
    float4 a = *(const float4*)p;
    float4 b = *(const float4*)(p + 4);
    frag_cast fc;
    fc.u = make_uint4(pack2(a.x, a.y), pack2(a.z, a.w),
                      pack2(b.x, b.y), pack2(b.z, b.w));
    return fc.v;
}

union SMem {
    struct {                       // phase 1: projection
        u16 Wt[64][136];           // W^T tile [n][k]
        u16 Cb[64][68];            // C-tile bounce buffer
    } p;
    struct {                       // phase 2: attention
        u16 Ks[2][32][136];
        u16 Vt[2][128][40];
        u16 Ps[64][40];
        float embs[512];
    } a;
};

__global__ __launch_bounds__(256, 3)
void fused_kernel(const float* __restrict__ q, const float* __restrict__ k,
                  const float* __restrict__ v, const float* __restrict__ Wq,
                  const float* __restrict__ Wk, const float* __restrict__ Wv,
                  const float* __restrict__ emb,
                  u16* __restrict__ Qp, u16* __restrict__ Kp, u16* __restrict__ VpT,
                  u32* __restrict__ cnt, float* __restrict__ out)
{
    __shared__ SMem sm;

    const int t = threadIdx.x;
    const int f = blockIdx.x;                  // 0..511
    const int lane = t & 63, w = t >> 6;
    const int L15 = lane & 15, quad = lane >> 4;

    // ================= PHASE 1: projection (6 tiles per block) ==============
    {
        const int xcd = f & 7, idx = f >> 3;   // idx 0..63
        const int mg = idx & 7, sub = idx >> 3;
        const int m0 = ((xcd << 3) + mg) << 6; // this block's X m-tile
        const int bb = m0 >> 11, sbase = m0 & 2047;

        #pragma unroll 1
        for (int s = 0; s < 6; ++s) {
            __syncthreads();                   // prior unit's Wt/Cb reads done
            const int rem = sub * 6 + s;       // 0..47
            const int which = rem >> 4, nt16 = rem & 15;
            const int nc0 = nt16 << 6;
            const float* x = (which == 0) ? q : (which == 1) ? k : v;
            const float* W = (which == 0) ? Wq : (which == 1) ? Wk : Wv;

            {   // stage W^T tile: coalesced fp32 row reads -> scalar bf16 LDS transpose
                const int kr = t >> 1, half = t & 1;
                const float* src = W + (size_t)kr * HDp + nc0 + half * 32;
                #pragma unroll
                for (int u = 0; u < 8; ++u) {
                    float4 a = *(const float4*)(src + u * 4);
                    const int nl = half * 32 + u * 4;
                    sm.p.Wt[nl + 0][kr] = f2bf(a.x);
                    sm.p.Wt[nl + 1][kr] = f2bf(a.y);
                    sm.p.Wt[nl + 2][kr] = f2bf(a.z);
                    sm.p.Wt[nl + 3][kr] = f2bf(a.w);
                }
            }
            // X A-frags for this wave's 16 rows (from L2 after first unit)
            bf16x8 xa[4];
            {
                const float* src = x + (size_t)(m0 + 16 * w + L15) * Dd + quad * 8;
                #pragma unroll
                for (int ks = 0; ks < 4; ++ks) xa[ks] = ldfrag_f32(src + ks * 32);
            }
            __syncthreads();

            f32x4 acc[4] = {};
            #pragma unroll
            for (int ks = 0; ks < 4; ++ks) {
                #pragma unroll
                for (int nt = 0; nt < 4; ++nt) {
                    bf16x8 b = *(const bf16x8*)&sm.p.Wt[nt * 16 + L15][ks * 32 + quad * 8];
                    acc[nt] = __builtin_amdgcn_mfma_f32_16x16x32_bf16(xa[ks], b, acc[nt], 0, 0, 0);
                }
            }
            // write C-tile to LDS (scalar), orientation per destination
            if (which < 2) {                   // Cb[ss_loc][nc_loc]
                #pragma unroll
                for (int nt = 0; nt < 4; ++nt)
                    #pragma unroll
                    for (int r = 0; r < 4; ++r)
                        sm.p.Cb[16 * w + quad * 4 + r][nt * 16 + L15] = f2bf(acc[nt][r]);
            } else {                           // Cb[nc_loc][ss_loc]
                #pragma unroll
                for (int nt = 0; nt < 4; ++nt)
                    #pragma unroll
                    for (int r = 0; r < 4; ++r)
                        sm.p.Cb[nt * 16 + L15][16 * w + quad * 4 + r] = f2bf(acc[nt][r]);
            }
            __syncthreads();

            // coalesced stores: 64 rows x 64 cols, 32B per thread
            const int row = t >> 2, c0 = (t & 3) << 4;
            uint4 d0 = *(const uint4*)&sm.p.Cb[row][c0];
            uint4 d1 = *(const uint4*)&sm.p.Cb[row][c0 + 8];
            if (which < 2) {
                const int hh = nc0 >> 7, dd = (nc0 & 127) + c0;
                u16* dst = (which == 0) ? Qp : Kp;
                u16* o = dst + ((size_t)((bb * Hh + hh) * Ssz + sbase + row)) * Dd + dd;
                *(uint4*)o = d0; *(uint4*)(o + 8) = d1;
            } else {
                const int ncg = nc0 + row;
                const int hh = ncg >> 7, dd = ncg & 127;
                u16* o = VpT + ((size_t)((bb * Hh + hh) * Dd + dd)) * Ssz + sbase + c0;
                *(uint4*)o = d0; *(uint4*)(o + 8) = d1;
            }
        }
    }

    // ================= grid-wide sync (all 512 blocks resident) =============
    __threadfence();
    __syncthreads();
    if (t == 0) {
        __hip_atomic_fetch_add(cnt, 1u, __ATOMIC_RELEASE, __HIP_MEMORY_SCOPE_AGENT);
        while (__hip_atomic_load(cnt, __ATOMIC_ACQUIRE, __HIP_MEMORY_SCOPE_AGENT) < NBLK)
            __builtin_amdgcn_s_sleep(8);
    }
    __syncthreads();
    __threadfence();

    // ================= PHASE 2: windowed flash attention ====================
    {
        const int xcd = f & 7, uu = f >> 3;
        const int g  = xcd + ((uu >> 5) << 3);   // combo 0..15 = b*8+h
        const int it = uu & 31;
        const int b = g >> 3, h = g & 7;
        const int i0 = it << 6;

        const size_t hoff = (size_t)(b * Hh + h) * Ssz * Dd;
        const u16* Qh = Qp + hoff;
        const u16* Kh = Kp + hoff;
        const u16* Vh = VpT + hoff;              // d-major [d][s]

        sm.a.embs[t] = emb[t]; sm.a.embs[t + 256] = emb[t + 256];

        const int rowlo = i0 + 16 * w;
        bf16x8 qf[4];
        {
            const u16* src = Qh + (size_t)(rowlo + L15) * Dd + quad * 8;
            #pragma unroll
            for (int ks = 0; ks < 4; ++ks)
                qf[ks] = *(const bf16x8*)(src + ks * 32);
        }

        const int kjr = t >> 3, kseg = t & 7;
        const int vdr = t >> 1, vseg = t & 1;
        uint4 kr[2], vr[2];
        auto loadKV = [&](int j0) {
            const u16* ks_ = Kh + (size_t)(j0 + kjr) * Dd + kseg * 16;
            kr[0] = *(const uint4*)(ks_);
            kr[1] = *(const uint4*)(ks_ + 8);
            const u16* vs_ = Vh + (size_t)vdr * Ssz + j0 + vseg * 16;
            vr[0] = *(const uint4*)(vs_);
            vr[1] = *(const uint4*)(vs_ + 8);
        };
        auto storeKV = [&](int bufi) {
            u16* kd = &sm.a.Ks[bufi][kjr][kseg * 16];
            *(uint4*)(kd)     = kr[0];
            *(uint4*)(kd + 8) = kr[1];
            u16* vd = &sm.a.Vt[bufi][vdr][vseg * 16];
            *(uint4*)(vd)     = vr[0];
            *(uint4*)(vd + 8) = vr[1];
        };

        const float scale = 0.08838834764831845f;
        float lsum[4] = {};
        f32x4 acc_o[8] = {};

        const int cbeg = (i0 >= 512) ? (i0 - 512) : 0;
        const int cend = i0 + 32;

        loadKV(cbeg);
        storeKV(0);
        __syncthreads();
        int buf = 0;
        for (int j0 = cbeg; j0 <= cend; j0 += 32) {
            const bool more = (j0 + 32 <= cend);
            if (more) loadKV(j0 + 32);

            f32x4 acc_s[2] = {};
            #pragma unroll
            for (int ks = 0; ks < 4; ++ks) {
                #pragma unroll
                for (int n16 = 0; n16 < 2; ++n16) {
                    bf16x8 bk = *(const bf16x8*)&sm.a.Ks[buf][n16 * 16 + L15][ks * 32 + quad * 8];
                    acc_s[n16] = __builtin_amdgcn_mfma_f32_16x16x32_bf16(qf[ks], bk, acc_s[n16], 0, 0, 0);
                }
            }

            #pragma unroll
            for (int r = 0; r < 4; ++r) {
                const int ig = rowlo + quad * 4 + r;
                const int d0 = ig - (j0 + L15);
                const int d1 = d0 - 16;
                const int i0x = min(max(d0 - 1, 0), 511);
                const int i1x = min(max(d1 - 1, 0), 511);
                const float sv0 = (d0 >= 1 && d0 <= 511) ? fmaf(acc_s[0][r], scale, sm.a.embs[i0x]) : -1e30f;
                const float sv1 = (d1 >= 1 && d1 <= 511) ? fmaf(acc_s[1][r], scale, sm.a.embs[i1x]) : -1e30f;
                const float p0 = __expf(sv0 - 8.0f);
                const float p1 = __expf(sv1 - 8.0f);
                lsum[r] += p0 + p1;
                sm.a.Ps[16 * w + quad * 4 + r][L15]      = f2bf(p0);
                sm.a.Ps[16 * w + quad * 4 + r][16 + L15] = f2bf(p1);
            }
            __builtin_amdgcn_sched_barrier(0);

            bf16x8 ap = *(const bf16x8*)&sm.a.Ps[16 * w + L15][quad * 8];
            #pragma unroll
            for (int nt = 0; nt < 8; ++nt) {
                bf16x8 bv = *(const bf16x8*)&sm.a.Vt[buf][nt * 16 + L15][quad * 8];
                acc_o[nt] = __builtin_amdgcn_mfma_f32_16x16x32_bf16(ap, bv, acc_o[nt], 0, 0, 0);
            }
            __builtin_amdgcn_sched_barrier(0);

            if (more) {
                storeKV(buf ^ 1);
                __syncthreads();
                buf ^= 1;
            }
        }

        #pragma unroll
        for (int r = 0; r < 4; ++r) {
            float rs = lsum[r];
            rs += __shfl_xor(rs, 1);
            rs += __shfl_xor(rs, 2);
            rs += __shfl_xor(rs, 4);
            rs += __shfl_xor(rs, 8);
            const int ig = rowlo + quad * 4 + r;
            float* o = out + ((size_t)(b * Ssz + ig)) * HDp + h * Dd;
            if (ig == 0) {
                #pragma unroll
                for (int nt = 0; nt < 8; ++nt)
                    o[nt * 16 + L15] = bflo((u32)Vh[(size_t)(nt * 16 + L15) * Ssz]);
            } else {
                const float inv = 1.0f / rs;
                #pragma unroll
                for (int nt = 0; nt < 8; ++nt)
                    o[nt * 16 + L15] = acc_o[nt][r] * inv;
            }
        }
    }
}

extern "C" void kernel_launch(void* const* d_in, const int* in_sizes, int n_in,
                              void* d_out, int out_size, void* d_ws, size_t ws_size,
                              hipStream_t stream)
{
    const float* q   = (const float*)d_in[0];
    const float* k   = (const float*)d_in[1];
    const float* v   = (const float*)d_in[2];
    const float* Wq  = (const float*)d_in[3];
    const float* Wk  = (const float*)d_in[4];
    const float* Wv  = (const float*)d_in[5];
    const float* emb = (const float*)d_in[6];
    float* out = (float*)d_out;

    // ws: [0,4) sync counter | [1KB,...) Qp/Kp/VpT bf16
    u32* cnt = (u32*)d_ws;
    const size_t per = (size_t)Bb * Hh * Ssz * Dd;
    u16* Qp  = (u16*)((char*)d_ws + 1024);
    u16* Kp  = Qp + per;
    u16* VpT = Kp + per;

    hipMemsetAsync(cnt, 0, 4, stream);
    fused_kernel<<<dim3(NBLK), dim3(256), 0, stream>>>(q, k, v, Wq, Wk, Wv, emb,
                                                       Qp, Kp, VpT, cnt, out);
}